// Round 8
// baseline (759.131 us; speedup 1.0000x reference)
//
#include <hip/hip_runtime.h>
#include <hip/hip_bf16.h>
#include <math.h>

typedef __hip_bfloat16 bf16;
typedef __attribute__((ext_vector_type(8))) short bf16x8;   // 8 bf16 = 4 VGPRs
typedef __attribute__((ext_vector_type(4))) float f32x4;

#define NT    32768   // total tokens
#define CH    320
#define NSEQ  2048
#define FRAMES 16
#define HEADS 8
#define DHEAD 40
#define INNER 1280
#define HW    1024
#define NIMG  32

__device__ __forceinline__ float b2f(bf16 v) { return __bfloat162float(v); }
__device__ __forceinline__ bf16  f2b(float v) { return __float2bfloat16(v); }
__device__ __forceinline__ float bfbits2f(unsigned short u) {
  union { unsigned int i; float f; } x; x.i = ((unsigned int)u) << 16; return x.f;
}
__device__ __forceinline__ unsigned short f2bfbits(float f) {
  union { float f; unsigned int i; } x; x.f = f;
  return (unsigned short)((x.i + 0x7FFF + ((x.i >> 16) & 1)) >> 16);
}

// async global->LDS 16B (wave-uniform base + lane*16)
__device__ __forceinline__ void stage16(const bf16* g, bf16* l) {
  __builtin_amdgcn_global_load_lds(
      (const __attribute__((address_space(1))) void*)g,
      (__attribute__((address_space(3))) void*)l, 16, 0, 0);
}

__device__ __forceinline__ float block_reduce_sum(float v, float* sbuf) {
  int lane = threadIdx.x & 63;
  int wv   = threadIdx.x >> 6;
#pragma unroll
  for (int off = 32; off; off >>= 1) v += __shfl_down(v, off);
  __syncthreads();
  if (lane == 0) sbuf[wv] = v;
  __syncthreads();
  int nw = ((int)blockDim.x + 63) >> 6;
  float r = 0.f;
  for (int i = 0; i < nw; ++i) r += sbuf[i];
  return r;
}

// ---- weight transpose+cast: [K][N] fp32 -> [N][K] bf16, batched ----
struct TD { const float* src; bf16* dst; int K, N, t0; };
struct TDs { TD d[12]; };
__global__ __launch_bounds__(256) void transpose_w_kernel(TDs td, int ndesc) {
  __shared__ float tile[32][33];
  int bt = blockIdx.x;
  int mi = 0;
  for (int i = 1; i < 12; ++i) if (i < ndesc && bt >= td.d[i].t0) mi = i;
  TD e = td.d[mi];
  int lt = bt - e.t0;
  int ntx = e.N >> 5;
  int kt = lt / ntx, nt = lt - kt * ntx;
#pragma unroll
  for (int q = 0; q < 4; ++q) {
    int idx = threadIdx.x + q * 256; int r = idx >> 5, c = idx & 31;
    tile[r][c] = e.src[(size_t)(kt * 32 + r) * e.N + nt * 32 + c];
  }
  __syncthreads();
#pragma unroll
  for (int q = 0; q < 4; ++q) {
    int idx = threadIdx.x + q * 256; int r = idx >> 5, c = idx & 31;
    e.dst[(size_t)(nt * 32 + r) * e.K + kt * 32 + c] = f2b(tile[c][r]);
  }
}

// ---- temporal positional-encoding table: pe[fi][c], 16x320 fp32 ----
__global__ __launch_bounds__(256) void pe_table_kernel(float* __restrict__ petab) {
  int i = blockIdx.x * 256 + threadIdx.x;
  if (i < 16 * CH) {
    int fi = i / CH, c = i - fi * CH;
    float arg = (float)fi * expf((float)(c & ~1) * -0.028782313662425575f);
    petab[i] = (c & 1) ? cosf(arg) : sinf(arg);
  }
}

// ---- wave-per-row LayerNorm; mode 0: plain; mode 1: +PE, temporal scatter ----
__global__ __launch_bounds__(256) void ln_fused_kernel(const bf16* __restrict__ in,
                                                       const float* __restrict__ w,
                                                       const float* __restrict__ b,
                                                       bf16* __restrict__ out,
                                                       const float* __restrict__ petab,
                                                       int mode) {
  int wv = threadIdx.x >> 6, lane = threadIdx.x & 63;
  int row = blockIdx.x * 4 + wv;
  size_t base = (size_t)row * CH;
  float v[5];
  float s = 0.f;
#pragma unroll
  for (int j = 0; j < 5; ++j) {
    v[j] = b2f(in[base + lane + 64 * j]);
    s += v[j];
  }
#pragma unroll
  for (int off = 32; off; off >>= 1) s += __shfl_down(s, off);
  float mean = __shfl(s, 0) * (1.f / 320.f);
  float s2 = 0.f;
#pragma unroll
  for (int j = 0; j < 5; ++j) { float d = v[j] - mean; s2 += d * d; }
#pragma unroll
  for (int off = 32; off; off >>= 1) s2 += __shfl_down(s2, off);
  float rstd = rsqrtf(__shfl(s2, 0) * (1.f / 320.f) + 1e-5f);
  size_t obase = base;
  const float* pe = nullptr;
  if (mode) {
    int img = row >> 10, dd = row & 1023, bb = img >> 4, fi = img & 15;
    int trow = (((bb << 10) + dd) << 4) + fi;
    obase = (size_t)trow * CH;
    pe = petab + fi * CH;
  }
#pragma unroll
  for (int j = 0; j < 5; ++j) {
    int c = lane + 64 * j;
    float o = (v[j] - mean) * rstd * w[c] + b[c];
    if (mode) o += pe[c];
    out[obase + c] = f2b(o);
  }
}

// ---- MFMA GEMM: C = A[M,K] @ BT[N,K]^T (+bias) (+res) ----
// BM=128 BN=160 BK=64; 4 waves (2x2), wave tile 64x80 (acc[4][5]).
// Output width always 320 (QKV: N=960 -> dst split by n0/320).
// rowmap 0: direct bf16; 1: temporal->spatial scatter bf16 (+res bf16);
// rowmap 2: fp32 transposed out[im][c][s] + fp32 residual (float4 stores).
__global__ __launch_bounds__(256) void gemm_mfma_kernel(
    const bf16* __restrict__ A, const bf16* __restrict__ BT,
    const float* __restrict__ bias, const bf16* res,
    bf16* C0, bf16* C1, bf16* C2,
    const float* __restrict__ resF, float* __restrict__ outF,
    int M, int K, int rowmap) {
  __shared__ __align__(16) bf16 sA[128 * 64];   // 16 KB
  __shared__ __align__(16) bf16 sB[160 * 64];   // 20 KB
  int tid = threadIdx.x, lane = tid & 63, w = tid >> 6;
  int wm = w >> 1, wn = w & 1;
  int m0 = blockIdx.x * 128, n0 = blockIdx.y * 160;
  int which = n0 / 320;
  int ncol0 = n0 - which * 320;
  bf16* C = which == 0 ? C0 : (which == 1 ? C1 : C2);
  f32x4 acc[4][5];
#pragma unroll
  for (int i = 0; i < 4; ++i)
#pragma unroll
    for (int j = 0; j < 5; ++j) acc[i][j] = (f32x4){0.f, 0.f, 0.f, 0.f};

  int lr = lane >> 3;
  int cg = (lane & 7) ^ lr;
  for (int k0 = 0; k0 < K; k0 += 64) {
#pragma unroll
    for (int s = 0; s < 4; ++s) {           // A: 16 chunks, 4/wave
      int tA = w * 4 + s;
      int row = tA * 8 + lr;
      stage16(A + (size_t)(m0 + row) * K + k0 + cg * 8, sA + tA * 512);
    }
#pragma unroll
    for (int s = 0; s < 5; ++s) {           // B: 20 chunks, 5/wave
      int tB = w * 5 + s;
      int row = tB * 8 + lr;
      stage16(BT + (size_t)(n0 + row) * K + k0 + cg * 8, sB + tB * 512);
    }
    __syncthreads();
#pragma unroll
    for (int kk = 0; kk < 2; ++kk) {
      bf16x8 a[4], b[5];
      int cc = kk * 4 + (lane >> 4);
#pragma unroll
      for (int i = 0; i < 4; ++i) {
        int r = wm * 64 + i * 16 + (lane & 15);
        a[i] = *(const bf16x8*)(sA + r * 64 + ((cc ^ (r & 7)) * 8));
      }
#pragma unroll
      for (int j = 0; j < 5; ++j) {
        int n = wn * 80 + j * 16 + (lane & 15);
        b[j] = *(const bf16x8*)(sB + n * 64 + ((cc ^ (n & 7)) * 8));
      }
#pragma unroll
      for (int i = 0; i < 4; ++i)
#pragma unroll
        for (int j = 0; j < 5; ++j)
          acc[i][j] = __builtin_amdgcn_mfma_f32_16x16x32_bf16(a[i], b[j], acc[i][j], 0, 0, 0);
    }
    __syncthreads();
  }
#pragma unroll
  for (int i = 0; i < 4; ++i)
#pragma unroll
    for (int j = 0; j < 5; ++j) {
      int row0 = m0 + wm * 64 + i * 16 + (lane >> 4) * 4;
      int col  = ncol0 + wn * 80 + j * 16 + (lane & 15);
      float bv = bias ? bias[col] : 0.f;
      if (rowmap == 2) {
        // tokens row0..row0+3 are 4 consecutive s within one image
        int im = row0 >> 10, s0r = row0 & 1023;
        size_t oidx = ((size_t)(im * 320 + col) << 10) + s0r;
        float4 xr = *(const float4*)(resF + oidx);
        float4 ov;
        ov.x = acc[i][j][0] + bv + xr.x;
        ov.y = acc[i][j][1] + bv + xr.y;
        ov.z = acc[i][j][2] + bv + xr.z;
        ov.w = acc[i][j][3] + bv + xr.w;
        *(float4*)(outF + oidx) = ov;
      } else {
#pragma unroll
        for (int rg = 0; rg < 4; ++rg) {
          int r = row0 + rg;
          if (rowmap == 1) {  // temporal row -> spatial row
            int n = r >> 4, fi = r & 15, bb = n >> 10, dd = n & 1023;
            r = ((bb << 4) + fi) * 1024 + dd;
          }
          size_t idx = (size_t)r * 320 + col;
          float v = acc[i][j][rg] + bv;
          if (res) v += b2f(res[idx]);
          C[idx] = f2b(v);
        }
      }
    }
}

// ---- MFMA GEGLU GEMM: BM=128 BN=128(a)+128(g) BK=64 ----
__global__ __launch_bounds__(256) void gemm_mfma_geglu_kernel(
    const bf16* __restrict__ A, const bf16* __restrict__ BT,
    const float* __restrict__ b1, bf16* __restrict__ act, int M, int K) {
  __shared__ __align__(16) bf16 sA[128 * 64];    // 16 KB
  __shared__ __align__(16) bf16 sBa[128 * 64];   // 16 KB
  __shared__ __align__(16) bf16 sBg[128 * 64];   // 16 KB
  int tid = threadIdx.x, lane = tid & 63, w = tid >> 6;
  int wm = w >> 1, wn = w & 1;
  int m0 = blockIdx.x * 128, n0 = blockIdx.y * 128;
  f32x4 aa[4][4], ag[4][4];
#pragma unroll
  for (int i = 0; i < 4; ++i)
#pragma unroll
    for (int j = 0; j < 4; ++j) {
      aa[i][j] = (f32x4){0.f, 0.f, 0.f, 0.f};
      ag[i][j] = (f32x4){0.f, 0.f, 0.f, 0.f};
    }
  int lr = lane >> 3;
  int cg = (lane & 7) ^ lr;
  for (int k0 = 0; k0 < K; k0 += 64) {
#pragma unroll
    for (int s = 0; s < 4; ++s) {
      int tA = w * 4 + s;
      int row = tA * 8 + lr;
      stage16(A + (size_t)(m0 + row) * K + k0 + cg * 8, sA + tA * 512);
    }
#pragma unroll
    for (int s = 0; s < 4; ++s) {
      int tB = w * 4 + s;
      int row = tB * 8 + lr;
      stage16(BT + (size_t)(n0 + row) * K + k0 + cg * 8, sBa + tB * 512);
      stage16(BT + (size_t)(1280 + n0 + row) * K + k0 + cg * 8, sBg + tB * 512);
    }
    __syncthreads();
#pragma unroll
    for (int kk = 0; kk < 2; ++kk) {
      bf16x8 a[4], ba[4], bg[4];
      int cc = kk * 4 + (lane >> 4);
#pragma unroll
      for (int i = 0; i < 4; ++i) {
        int r = wm * 64 + i * 16 + (lane & 15);
        a[i] = *(const bf16x8*)(sA + r * 64 + ((cc ^ (r & 7)) * 8));
      }
#pragma unroll
      for (int j = 0; j < 4; ++j) {
        int n = wn * 64 + j * 16 + (lane & 15);
        ba[j] = *(const bf16x8*)(sBa + n * 64 + ((cc ^ (n & 7)) * 8));
        bg[j] = *(const bf16x8*)(sBg + n * 64 + ((cc ^ (n & 7)) * 8));
      }
#pragma unroll
      for (int i = 0; i < 4; ++i)
#pragma unroll
        for (int j = 0; j < 4; ++j) {
          aa[i][j] = __builtin_amdgcn_mfma_f32_16x16x32_bf16(a[i], ba[j], aa[i][j], 0, 0, 0);
          ag[i][j] = __builtin_amdgcn_mfma_f32_16x16x32_bf16(a[i], bg[j], ag[i][j], 0, 0, 0);
        }
    }
    __syncthreads();
  }
#pragma unroll
  for (int i = 0; i < 4; ++i)
#pragma unroll
    for (int j = 0; j < 4; ++j) {
      int row0 = m0 + wm * 64 + i * 16 + (lane >> 4) * 4;
      int col  = n0 + wn * 64 + j * 16 + (lane & 15);
      float bva = b1[col], bvg = b1[1280 + col];
#pragma unroll
      for (int rg = 0; rg < 4; ++rg) {
        float av = aa[i][j][rg] + bva;
        float gv = ag[i][j][rg] + bvg;
        float gelu = 0.5f * gv * (1.0f + erff(gv * 0.70710678118654752f));
        act[(size_t)(row0 + rg) * 1280 + col] = f2b(av * gelu);
      }
    }
}

// ---- GroupNorm stats ----
__global__ __launch_bounds__(256) void gn_stats_kernel(const float* __restrict__ x,
                                                       float* __restrict__ stat) {
  __shared__ float sbuf[8];
  int g  = blockIdx.x;
  int im = blockIdx.y;
  const float* base = x + ((size_t)im * CH + (size_t)g * 10) * HW;
  float s = 0.f, s2 = 0.f;
  for (int i = threadIdx.x; i < 10 * HW; i += 256) {
    float v = base[i];
    s += v; s2 += v * v;
  }
  s  = block_reduce_sum(s, sbuf);
  s2 = block_reduce_sum(s2, sbuf);
  if (threadIdx.x == 0) {
    float mean = s * (1.f / 10240.f);
    float var  = s2 * (1.f / 10240.f) - mean * mean;
    stat[(im * 32 + g) * 2 + 0] = mean;
    stat[(im * 32 + g) * 2 + 1] = rsqrtf(var + 1e-6f);
  }
}

// ---- GN apply + transpose -> tokens ----
__global__ __launch_bounds__(256) void gn_apply_kernel(const float* __restrict__ x,
                                                       const float* __restrict__ gw,
                                                       const float* __restrict__ gb,
                                                       const float* __restrict__ stat,
                                                       bf16* __restrict__ xn) {
  __shared__ float tile[32][33];
  int st = blockIdx.x, ct = blockIdx.y, im = blockIdx.z;
  int c0 = ct * 32, s0 = st * 32;
  for (int t = threadIdx.x; t < 1024; t += 256) {
    int i = t >> 5, j = t & 31;
    int c = c0 + i;
    int g = c / 10;
    float mean = stat[(im * 32 + g) * 2 + 0];
    float rstd = stat[(im * 32 + g) * 2 + 1];
    tile[i][j] = (x[((size_t)(im * CH + c) << 10) + s0 + j] - mean) * rstd * gw[c] + gb[c];
  }
  __syncthreads();
  for (int t = threadIdx.x; t < 1024; t += 256) {
    int i = t >> 5, j = t & 31;
    xn[((size_t)(im * HW + s0 + i)) * CH + c0 + j] = f2b(tile[j][i]);
  }
}

// ---- temporal attention: one block per sequence, conflict-aware fp32 LDS ----
#define AROW 324   // 324%32=4 (bank-spread), 16B-aligned
__global__ __launch_bounds__(256) void attention_kernel(const bf16* __restrict__ Q,
                                                        const bf16* __restrict__ K,
                                                        const bf16* __restrict__ V,
                                                        bf16* __restrict__ O) {
  __shared__ float q[16 * AROW];
  __shared__ float k[16 * AROW];
  __shared__ float v[16 * AROW];
  __shared__ float sc[HEADS * 16 * 16];
  const float SCALE = 0.15811388300841897f;
  int tid = threadIdx.x;
  int n = blockIdx.x;
  size_t base = (size_t)n * FRAMES * CH;
  for (int j = tid; j < 1280; j += 256) {
    int row = j / 80, off = (j - row * 80) * 4;
    int src = row * 320 + off;
    ushort4 uq = *(const ushort4*)(Q + base + src);
    ushort4 uk = *(const ushort4*)(K + base + src);
    ushort4 uv = *(const ushort4*)(V + base + src);
    float* qd = &q[row * AROW + off];
    float* kd = &k[row * AROW + off];
    float* vd = &v[row * AROW + off];
    qd[0] = bfbits2f(uq.x) * SCALE; qd[1] = bfbits2f(uq.y) * SCALE;
    qd[2] = bfbits2f(uq.z) * SCALE; qd[3] = bfbits2f(uq.w) * SCALE;
    kd[0] = bfbits2f(uk.x); kd[1] = bfbits2f(uk.y);
    kd[2] = bfbits2f(uk.z); kd[3] = bfbits2f(uk.w);
    vd[0] = bfbits2f(uv.x); vd[1] = bfbits2f(uv.y);
    vd[2] = bfbits2f(uv.z); vd[3] = bfbits2f(uv.w);
  }
  __syncthreads();
  {
    int h = tid >> 5, sub = tid & 31, qf = sub >> 1, kfg = sub & 1;
    const float* qrow = &q[qf * AROW + h * DHEAD];
    float s[8] = {0.f, 0.f, 0.f, 0.f, 0.f, 0.f, 0.f, 0.f};
#pragma unroll
    for (int d4 = 0; d4 < 10; ++d4) {
      float4 qv = *(const float4*)(qrow + d4 * 4);
#pragma unroll
      for (int i = 0; i < 8; ++i) {
        const float* krow = &k[(kfg * 8 + i) * AROW + h * DHEAD];
        float4 kv = *(const float4*)(krow + d4 * 4);
        s[i] += qv.x * kv.x + qv.y * kv.y + qv.z * kv.z + qv.w * kv.w;
      }
    }
    float* dst = &sc[(h * 16 + qf) * 16 + kfg * 8];
#pragma unroll
    for (int i = 0; i < 8; ++i) dst[i] = s[i];
  }
  __syncthreads();
  if (tid < 128) {
    float* r = &sc[tid * 16];
    float mx = r[0];
#pragma unroll
    for (int i = 1; i < 16; ++i) mx = fmaxf(mx, r[i]);
    float sum = 0.f;
#pragma unroll
    for (int i = 0; i < 16; ++i) { float e = expf(r[i] - mx); r[i] = e; sum += e; }
    float inv = 1.0f / sum;
#pragma unroll
    for (int i = 0; i < 16; ++i) r[i] *= inv;
  }
  __syncthreads();
  for (int g = tid; g < 1280; g += 256) {
    int qf = g / 80, c4 = g - qf * 80;
    int h = c4 / 10;
    const float* p = &sc[(h * 16 + qf) * 16];
    float4 o = {0.f, 0.f, 0.f, 0.f};
#pragma unroll
    for (int kf = 0; kf < 16; ++kf) {
      float pv = p[kf];
      float4 vv = *(const float4*)&v[kf * AROW + c4 * 4];
      o.x += pv * vv.x; o.y += pv * vv.y; o.z += pv * vv.z; o.w += pv * vv.w;
    }
    ushort4 u;
    u.x = f2bfbits(o.x); u.y = f2bfbits(o.y);
    u.z = f2bfbits(o.z); u.w = f2bfbits(o.w);
    *(ushort4*)(O + base + qf * 320 + c4 * 4) = u;
  }
}

extern "C" void kernel_launch(void* const* d_in, const int* in_sizes, int n_in,
                              void* d_out, int out_size, void* d_ws, size_t ws_size,
                              hipStream_t stream) {
  const float* x      = (const float*)d_in[0];
  const float* gn_w   = (const float*)d_in[1];
  const float* gn_b   = (const float*)d_in[2];
  const float* pin_w  = (const float*)d_in[3];
  const float* pin_b  = (const float*)d_in[4];
  const float* ffln_w = (const float*)d_in[19];
  const float* ffln_b = (const float*)d_in[20];
  const float* ff_w1  = (const float*)d_in[21];
  const float* ff_b1  = (const float*)d_in[22];
  const float* ff_w2  = (const float*)d_in[23];
  const float* ff_b2  = (const float*)d_in[24];
  const float* pout_w = (const float*)d_in[25];
  const float* pout_b = (const float*)d_in[26];

  const size_t NTC = (size_t)NT * CH;
  bf16* W0 = (bf16*)d_ws;              // hs residual stream (spatial order)
  bf16* W1 = W0 + NTC;
  bf16* W2 = W1 + NTC;
  bf16* W3 = W2 + NTC;
  bf16* OB = (bf16*)d_out;             // scratch (K buffer) until pout
  float* gnstat = (float*)d_out;
  bf16* WT = (bf16*)d_out + NTC;       // transposed weights (dead before pout)
  bf16* wt_pin  = WT;
  bf16* wt_qkv1 = wt_pin + 102400;
  bf16* wt_wo1  = wt_qkv1 + 307200;
  bf16* wt_qkv2 = wt_wo1 + 102400;
  bf16* wt_wo2  = wt_qkv2 + 307200;
  bf16* wt_ff1  = wt_wo2 + 102400;     // 2560x320
  bf16* wt_ff2  = wt_ff1 + 819200;     // 320x1280
  float* petab  = (float*)(wt_ff2 + 409600);  // 16x320 fp32

  TDs td; int t0 = 0;
  auto add = [&](int i, const float* s, bf16* d, int K, int N) {
    td.d[i] = {s, d, K, N, t0}; t0 += (K / 32) * (N / 32);
  };
  add(0, pin_w, wt_pin, 320, 320);
  add(1, (const float*)d_in[7],  wt_qkv1,          320, 320);
  add(2, (const float*)d_in[8],  wt_qkv1 + 102400, 320, 320);
  add(3, (const float*)d_in[9],  wt_qkv1 + 204800, 320, 320);
  add(4, (const float*)d_in[10], wt_wo1,           320, 320);
  add(5, (const float*)d_in[14], wt_qkv2,          320, 320);
  add(6, (const float*)d_in[15], wt_qkv2 + 102400, 320, 320);
  add(7, (const float*)d_in[16], wt_qkv2 + 204800, 320, 320);
  add(8, (const float*)d_in[17], wt_wo2,           320, 320);
  add(9, ff_w1, wt_ff1, 320, 2560);
  add(10, ff_w2, wt_ff2, 1280, 320);
  td.d[11] = td.d[0];
  transpose_w_kernel<<<t0, 256, 0, stream>>>(td, 11);
  pe_table_kernel<<<20, 256, 0, stream>>>(petab);

  dim3 g_trans(32, 10, NIMG);
  dim3 g_gemm(NT / 128, 2);            // N=320 -> 2 tiles of 160

  gn_stats_kernel<<<dim3(32, NIMG), 256, 0, stream>>>(x, gnstat);
  gn_apply_kernel<<<g_trans, 256, 0, stream>>>(x, gn_w, gn_b, gnstat, W1);
  gemm_mfma_kernel<<<g_gemm, 256, 0, stream>>>(W1, wt_pin, pin_b, nullptr,
                                               W0, W0, W0, nullptr, nullptr, NT, CH, 0);

  for (int blk = 0; blk < 2; ++blk) {
    const float* lnw = (const float*)d_in[5 + 7 * blk];
    const float* lnb = (const float*)d_in[6 + 7 * blk];
    const float* bo  = (const float*)d_in[11 + 7 * blk];
    bf16* wt_qkv = blk ? wt_qkv2 : wt_qkv1;
    bf16* wt_wo  = blk ? wt_wo2  : wt_wo1;

    ln_fused_kernel<<<NT / 4, 256, 0, stream>>>(W0, lnw, lnb, W2, petab, 1);
    // fused QKV (N=960 -> 6 tiles): Q->W3, K->OB, V->W1 (temporal order)
    gemm_mfma_kernel<<<dim3(NT / 128, 6), 256, 0, stream>>>(W2, wt_qkv, nullptr, nullptr,
                                                            W3, OB, W1, nullptr, nullptr, NT, CH, 0);
    attention_kernel<<<NSEQ, 256, 0, stream>>>(W3, OB, W1, W2);
    // o-proj with fused rearrange-to-spatial + residual add into W0
    gemm_mfma_kernel<<<g_gemm, 256, 0, stream>>>(W2, wt_wo, bo, W0,
                                                 W0, W0, W0, nullptr, nullptr, NT, CH, 1);
  }

  ln_fused_kernel<<<NT / 4, 256, 0, stream>>>(W0, ffln_w, ffln_b, W1, nullptr, 0);
  const int MH = NT / 2;
  for (int h = 0; h < 2; ++h) {
    const bf16* Ah = W1 + (size_t)h * MH * CH;
    bf16* act = W2;  // MH*1280 across W2..W3
    gemm_mfma_geglu_kernel<<<dim3(MH / 128, 10), 256, 0, stream>>>(Ah, wt_ff1, ff_b1,
                                                                   act, MH, CH);
    bf16* hsh = W0 + (size_t)h * MH * CH;
    gemm_mfma_kernel<<<dim3(MH / 128, 2), 256, 0, stream>>>(act, wt_ff2, ff_b2, hsh,
                                                            hsh, hsh, hsh, nullptr, nullptr,
                                                            MH, INNER, 0);
  }

  // re-transpose pout weights into W1 (free now) since pout overwrites d_out
  TDs tdp; tdp.d[0] = {pout_w, W1, 320, 320, 0};
  for (int i = 1; i < 12; ++i) tdp.d[i] = tdp.d[0];
  transpose_w_kernel<<<100, 256, 0, stream>>>(tdp, 1);
  // proj_out fused with transpose-back + fp32 spatial residual -> d_out
  gemm_mfma_kernel<<<g_gemm, 256, 0, stream>>>(W0, W1, pout_b, nullptr,
                                               nullptr, nullptr, nullptr,
                                               x, (float*)d_out, NT, CH, 2);
}